// Round 7
// baseline (811.190 us; speedup 1.0000x reference)
//
#include <hip/hip_runtime.h>
#include <hip/hip_bf16.h>

// BasicAttn: B=2,H=8,S=4096,DK=64. Outputs: context (B,H,S,DK) f32 then attn (B,H,S,S) f32.
// Round 7: BISECTION. Split into lsum_kernel (pass A: QK-MFMA + exp + rowsum ->
// 256KB ws) and attn_kernel (pass B: recompute S, direct f32x4 attn stores from
// registers, PV via LDS transpose, ctx). Separate rocprof rows per pass tell us
// whether the ~730us pin lives in the compute/load pipeline or the store path.
// Both kernels: swapped-operand MFMA, XCD head affinity, K-half split across waves.

typedef __bf16 bf16x8 __attribute__((ext_vector_type(8)));
typedef __bf16 bf16x4 __attribute__((ext_vector_type(4)));
typedef float f32x4 __attribute__((ext_vector_type(4)));

#define BH 16
#define SEQ 4096
#define DKD 64
#define PSTRIDE 72
#define LOG2E 1.44269504088896f

__global__ void cvt_bf16_kernel(const float* __restrict__ src,
                                __bf16* __restrict__ dst, int n4, float scale) {
    int i = blockIdx.x * blockDim.x + threadIdx.x;
    if (i < n4) {
        const float4 v = reinterpret_cast<const float4*>(src)[i];
        bf16x4 o;
        o[0] = (__bf16)(v.x * scale); o[1] = (__bf16)(v.y * scale);
        o[2] = (__bf16)(v.z * scale); o[3] = (__bf16)(v.w * scale);
        reinterpret_cast<bf16x4*>(dst)[i] = o;
    }
}

// V[head][s][d] (f32) -> Vt[head][d][s] (bf16), 64x64 tiles through LDS.
__global__ void transpose_v_kernel(const float* __restrict__ V,
                                   __bf16* __restrict__ Vt) {
    __shared__ __bf16 T[DKD][72];
    const int head = blockIdx.y;
    const int s0 = blockIdx.x * 64;
    const int t = threadIdx.x;
    const float* vp = V + ((size_t)head * SEQ + s0) * DKD;
#pragma unroll
    for (int i = 0; i < 16; ++i) {
        int j = i * 256 + t;            // j = s*64 + d, coalesced read
        T[j & 63][j >> 6] = (__bf16)vp[j];
    }
    __syncthreads();
    __bf16* op = Vt + (size_t)head * DKD * SEQ + s0;
#pragma unroll
    for (int i = 0; i < 16; ++i) {
        int j = i * 256 + t;            // j = d*64 + s, coalesced write
        op[(size_t)(j >> 6) * SEQ + (j & 63)] = T[j >> 6][j & 63];
    }
}

// ---- Pass A: rowwise sum of exp2(scores) -> Lsum_ws[head*SEQ + qrow] ----
__global__ __launch_bounds__(256, 4) void lsum_kernel(
    const __bf16* __restrict__ Qb, const __bf16* __restrict__ Kb,
    float* __restrict__ Lsum_ws) {
    __shared__ float Lsum[4][16];

    const int tid = threadIdx.x;
    const int w = tid >> 6;
    const int lane = tid & 63;
    const int c16 = lane & 15;
    const int g = lane >> 4;
    const int qsub = w & 1;
    const int khalf = w >> 1;

    const int wg = blockIdx.x;
    const int head = ((wg & 7) << 1) | ((wg >> 3) & 1);
    const int qblk = wg >> 4;
    const int qbase = qblk * 32 + qsub * 16;
    const int tile0 = khalf * 32;

    const __bf16* qp = Qb + ((size_t)head * SEQ + qbase + c16) * DKD + g * 8;
    const bf16x8 qf0 = *reinterpret_cast<const bf16x8*>(qp);
    const bf16x8 qf1 = *reinterpret_cast<const bf16x8*>(qp + 32);
    const __bf16* kbase = Kb + (size_t)head * SEQ * DKD;

    float lsum = 0.f;
    for (int t = 0; t < 32; ++t) {
        const int kt = (tile0 + t) * 64;
#pragma unroll
        for (int ct = 0; ct < 4; ++ct) {
            const __bf16* kp = kbase + (size_t)(kt + ct * 16 + c16) * DKD + g * 8;
            bf16x8 kf0 = *reinterpret_cast<const bf16x8*>(kp);
            bf16x8 kf1 = *reinterpret_cast<const bf16x8*>(kp + 32);
            f32x4 a = (f32x4){0.f, 0.f, 0.f, 0.f};
            a = __builtin_amdgcn_mfma_f32_16x16x32_bf16(kf0, qf0, a, 0, 0, 0);
            a = __builtin_amdgcn_mfma_f32_16x16x32_bf16(kf1, qf1, a, 0, 0, 0);
            float e0 = __builtin_amdgcn_exp2f(a[0] * LOG2E);
            float e1 = __builtin_amdgcn_exp2f(a[1] * LOG2E);
            float e2 = __builtin_amdgcn_exp2f(a[2] * LOG2E);
            float e3 = __builtin_amdgcn_exp2f(a[3] * LOG2E);
            lsum += (e0 + e1) + (e2 + e3);
        }
    }
    lsum += __shfl_xor(lsum, 16);
    lsum += __shfl_xor(lsum, 32);
    if (g == 0) Lsum[w][c16] = lsum;
    __syncthreads();
    if (khalf == 0 && g == 0)
        Lsum_ws[(size_t)head * SEQ + qbase + c16] = Lsum[w][c16] + Lsum[w ^ 2][c16];
}

// ---- Pass B: recompute S, store attn from regs, PV, ctx ----
__global__ __launch_bounds__(256, 4) void attn_kernel(
    const __bf16* __restrict__ Qb, const __bf16* __restrict__ Kb,
    const __bf16* __restrict__ Vt, const float* __restrict__ Lsum_ws,
    float* __restrict__ out_ctx, float* __restrict__ out_attn) {
    // [buf][wave][q-row][key]; Pl[0] reused at the end as f32 PV-combine (8KB).
    __shared__ __align__(16) __bf16 Pl[2][4][16][PSTRIDE];

    const int tid = threadIdx.x;
    const int w = tid >> 6;
    const int lane = tid & 63;
    const int c16 = lane & 15;
    const int g = lane >> 4;
    const int qsub = w & 1;
    const int khalf = w >> 1;

    const int wg = blockIdx.x;
    const int head = ((wg & 7) << 1) | ((wg >> 3) & 1);
    const int qblk = wg >> 4;
    const int qbase = qblk * 32 + qsub * 16;
    const int tile0 = khalf * 32;

    const __bf16* qp = Qb + ((size_t)head * SEQ + qbase + c16) * DKD + g * 8;
    const bf16x8 qf0 = *reinterpret_cast<const bf16x8*>(qp);
    const bf16x8 qf1 = *reinterpret_cast<const bf16x8*>(qp + 32);

    const __bf16* kbase = Kb + (size_t)head * SEQ * DKD;
    const __bf16* vbase = Vt + (size_t)head * DKD * SEQ;
    float* attn_p = out_attn + ((size_t)head * SEQ + qbase) * SEQ;

    const float inv_l = __builtin_amdgcn_rcpf(Lsum_ws[(size_t)head * SEQ + qbase + c16]);

    f32x4 o[4];
#pragma unroll
    for (int dt = 0; dt < 4; ++dt) o[dt] = (f32x4){0.f, 0.f, 0.f, 0.f};

    // S-tile: lane computes keys ct*16+g*4..+3 of q-row c16.
    // attn stored DIRECTLY from registers (plain f32x4; 4 rows x 256B per instr =
    // full cachelines). bf16 P goes to LDS only for the PV fragment transpose.
    auto computeS = [&](int t, __bf16(*Pbuf)[PSTRIDE]) {
        const int kt = (tile0 + t) * 64;
        f32x4 acc[4];
#pragma unroll
        for (int ct = 0; ct < 4; ++ct) {
            acc[ct] = (f32x4){0.f, 0.f, 0.f, 0.f};
            const __bf16* kp = kbase + (size_t)(kt + ct * 16 + c16) * DKD + g * 8;
            bf16x8 kf0 = *reinterpret_cast<const bf16x8*>(kp);
            bf16x8 kf1 = *reinterpret_cast<const bf16x8*>(kp + 32);
            acc[ct] = __builtin_amdgcn_mfma_f32_16x16x32_bf16(kf0, qf0, acc[ct], 0, 0, 0);
            acc[ct] = __builtin_amdgcn_mfma_f32_16x16x32_bf16(kf1, qf1, acc[ct], 0, 0, 0);
        }
#pragma unroll
        for (int ct = 0; ct < 4; ++ct) {
            f32x4 p;
            bf16x4 pb;
#pragma unroll
            for (int r = 0; r < 4; ++r) {
                p[r] = __builtin_amdgcn_exp2f(acc[ct][r] * LOG2E) * inv_l;
                pb[r] = (__bf16)p[r];
            }
            *reinterpret_cast<f32x4*>(attn_p + (size_t)c16 * SEQ + kt + ct * 16 + g * 4) = p;
            *reinterpret_cast<bf16x4*>(&Pbuf[c16][ct * 16 + g * 4]) = pb;
        }
    };

    // PV: O^T += V^T(dt-tile) x P^T; lane accumulates dims dt*16+g*4..+3 of row c16.
    auto pvTile = [&](int t, const __bf16(*Pbuf)[PSTRIDE]) {
        const int kt = (tile0 + t) * 64;
        bf16x8 pb0 = *reinterpret_cast<const bf16x8*>(&Pbuf[c16][g * 8]);
        bf16x8 pb1 = *reinterpret_cast<const bf16x8*>(&Pbuf[c16][g * 8 + 32]);
#pragma unroll
        for (int dt = 0; dt < 4; ++dt) {
            const __bf16* vp = vbase + (size_t)(dt * 16 + c16) * SEQ + kt + g * 8;
            bf16x8 vf0 = *reinterpret_cast<const bf16x8*>(vp);
            bf16x8 vf1 = *reinterpret_cast<const bf16x8*>(vp + 32);
            o[dt] = __builtin_amdgcn_mfma_f32_16x16x32_bf16(vf0, pb0, o[dt], 0, 0, 0);
            o[dt] = __builtin_amdgcn_mfma_f32_16x16x32_bf16(vf1, pb1, o[dt], 0, 0, 0);
        }
    };

    // Software-pipelined, double-buffered (wave-private LDS slices, no fences).
    computeS(0, Pl[0][w]);
    for (int t = 1; t < 31; t += 2) {
        computeS(t, Pl[1][w]);
        pvTile(t - 1, Pl[0][w]);
        computeS(t + 1, Pl[0][w]);
        pvTile(t, Pl[1][w]);
    }
    computeS(31, Pl[1][w]);
    pvTile(30, Pl[0][w]);
    pvTile(31, Pl[1][w]);

    // Combine PV partials across the K-half wave pair (reuse Pl[0] as f32).
    __syncthreads();
    float* Of = reinterpret_cast<float*>(&Pl[0][0][0][0]);
    float* my = Of + ((size_t)qsub * 16 + c16) * 64;
    if (khalf == 1) {
#pragma unroll
        for (int dt = 0; dt < 4; ++dt)
            *reinterpret_cast<f32x4*>(my + dt * 16 + g * 4) = o[dt];
    }
    __syncthreads();
    if (khalf == 0) {
        float* ctx_p = out_ctx + ((size_t)head * SEQ + qbase) * DKD;
#pragma unroll
        for (int dt = 0; dt < 4; ++dt) {
            f32x4 p = *reinterpret_cast<const f32x4*>(my + dt * 16 + g * 4);
            o[dt] += p;
            *reinterpret_cast<f32x4*>(ctx_p + (size_t)c16 * DKD + dt * 16 + g * 4) = o[dt];
        }
    }
}

extern "C" void kernel_launch(void* const* d_in, const int* in_sizes, int n_in,
                              void* d_out, int out_size, void* d_ws, size_t ws_size,
                              hipStream_t stream) {
    const float* Q = (const float*)d_in[0];
    const float* K = (const float*)d_in[1];
    const float* V = (const float*)d_in[2];
    float* out = (float*)d_out;

    const size_t nElem = (size_t)BH * SEQ * DKD;  // 4,194,304
    __bf16* Qb = (__bf16*)d_ws;
    __bf16* Kb = Qb + nElem;
    __bf16* Vt = Kb + nElem;
    float* Lsum_ws = reinterpret_cast<float*>(Vt + nElem);  // BH*SEQ f32 = 256KB

    float* out_ctx = out;
    float* out_attn = out + nElem;  // context first, then attn

    const int n4 = (int)(nElem / 4);
    cvt_bf16_kernel<<<dim3((n4 + 255) / 256), dim3(256), 0, stream>>>(Q, Qb, n4, 0.125f);
    cvt_bf16_kernel<<<dim3((n4 + 255) / 256), dim3(256), 0, stream>>>(K, Kb, n4, 1.0f);
    transpose_v_kernel<<<dim3(64, BH), dim3(256), 0, stream>>>(V, Vt);
    lsum_kernel<<<dim3(BH * SEQ / 32), dim3(256), 0, stream>>>(Qb, Kb, Lsum_ws);
    attn_kernel<<<dim3(BH * SEQ / 32), dim3(256), 0, stream>>>(Qb, Kb, Vt, Lsum_ws,
                                                               out_ctx, out_attn);
}

// Round 8
// 803.689 us; speedup vs baseline: 1.0093x; 1.0093x over previous
//
#include <hip/hip_runtime.h>
#include <hip/hip_bf16.h>

// BasicAttn: B=2,H=8,S=4096,DK=64. Outputs: context (B,H,S,DK) f32 then attn (B,H,S,S) f32.
// Round 8: OCCUPANCY. Empirical law: waves/SIMD ~ 256/VGPR (r5: 32 VGPR->81% occ,
// r4/r6: 64 VGPR->~45%). Target VGPR<=51 via launch_bounds(128,5) + halved live
// accumulators (32-key S-halves). Fused two-pass, 2 waves/block (2 q-subtiles,
// full K), ZERO barriers, no K-split, direct-from-register attn stores.
// Swapped-operand MFMA throughout; XCD head affinity kept.

typedef __bf16 bf16x8 __attribute__((ext_vector_type(8)));
typedef __bf16 bf16x4 __attribute__((ext_vector_type(4)));
typedef float f32x4 __attribute__((ext_vector_type(4)));

#define BH 16
#define SEQ 4096
#define DKD 64
#define PSTRIDE 72
#define LOG2E 1.44269504088896f

__global__ void cvt_bf16_kernel(const float* __restrict__ src,
                                __bf16* __restrict__ dst, int n4, float scale) {
    int i = blockIdx.x * blockDim.x + threadIdx.x;
    if (i < n4) {
        const float4 v = reinterpret_cast<const float4*>(src)[i];
        bf16x4 o;
        o[0] = (__bf16)(v.x * scale); o[1] = (__bf16)(v.y * scale);
        o[2] = (__bf16)(v.z * scale); o[3] = (__bf16)(v.w * scale);
        reinterpret_cast<bf16x4*>(dst)[i] = o;
    }
}

// V[head][s][d] (f32) -> Vt[head][d][s] (bf16), 64x64 tiles through LDS.
__global__ void transpose_v_kernel(const float* __restrict__ V,
                                   __bf16* __restrict__ Vt) {
    __shared__ __bf16 T[DKD][72];
    const int head = blockIdx.y;
    const int s0 = blockIdx.x * 64;
    const int t = threadIdx.x;
    const float* vp = V + ((size_t)head * SEQ + s0) * DKD;
#pragma unroll
    for (int i = 0; i < 16; ++i) {
        int j = i * 256 + t;            // j = s*64 + d, coalesced read
        T[j & 63][j >> 6] = (__bf16)vp[j];
    }
    __syncthreads();
    __bf16* op = Vt + (size_t)head * DKD * SEQ + s0;
#pragma unroll
    for (int i = 0; i < 16; ++i) {
        int j = i * 256 + t;            // j = d*64 + s, coalesced write
        op[(size_t)(j >> 6) * SEQ + (j & 63)] = T[j >> 6][j & 63];
    }
}

__global__ __launch_bounds__(128, 5) void attn_kernel(
    const __bf16* __restrict__ Qb, const __bf16* __restrict__ Kb,
    const __bf16* __restrict__ Vt, float* __restrict__ out_ctx,
    float* __restrict__ out_attn) {
    // [buf][wave][q-row][key] bf16 P staging for the PV fragment transpose.
    __shared__ __align__(16) __bf16 Pl[2][2][16][PSTRIDE];

    const int tid = threadIdx.x;
    const int w = tid >> 6;      // 2 waves = 2 q-subtiles
    const int lane = tid & 63;
    const int c16 = lane & 15;   // q-row within the wave's 16-row tile
    const int g = lane >> 4;     // key/dim 4-group (0..3)

    // XCD head affinity: xcd = wg % 8 serves heads {2*xcd, 2*xcd+1}.
    const int wg = blockIdx.x;
    const int head = ((wg & 7) << 1) | ((wg >> 3) & 1);
    const int qblk = wg >> 4;               // 0..127 (32-row blocks)
    const int qbase = qblk * 32 + w * 16;

    // Q fragments (B operand of swapped QK^T): Q[qbase+c16][g*8..+7], scaled 1/8.
    const __bf16* qp = Qb + ((size_t)head * SEQ + qbase + c16) * DKD + g * 8;
    const bf16x8 qf0 = *reinterpret_cast<const bf16x8*>(qp);
    const bf16x8 qf1 = *reinterpret_cast<const bf16x8*>(qp + 32);

    const __bf16* kbase = Kb + (size_t)head * SEQ * DKD;
    const __bf16* vbase = Vt + (size_t)head * DKD * SEQ;
    float* attn_p = out_attn + ((size_t)head * SEQ + qbase) * SEQ;

    // ---- Pass A: per-lane sum of exp2 over all keys (low reg pressure) ----
    float lsum = 0.f;
    for (int t = 0; t < 64; ++t) {
        const int kt = t * 64;
#pragma unroll
        for (int ct = 0; ct < 4; ++ct) {
            const __bf16* kp = kbase + (size_t)(kt + ct * 16 + c16) * DKD + g * 8;
            bf16x8 kf0 = *reinterpret_cast<const bf16x8*>(kp);
            bf16x8 kf1 = *reinterpret_cast<const bf16x8*>(kp + 32);
            f32x4 a = (f32x4){0.f, 0.f, 0.f, 0.f};
            a = __builtin_amdgcn_mfma_f32_16x16x32_bf16(kf0, qf0, a, 0, 0, 0);
            a = __builtin_amdgcn_mfma_f32_16x16x32_bf16(kf1, qf1, a, 0, 0, 0);
            float e0 = __builtin_amdgcn_exp2f(a[0] * LOG2E);
            float e1 = __builtin_amdgcn_exp2f(a[1] * LOG2E);
            float e2 = __builtin_amdgcn_exp2f(a[2] * LOG2E);
            float e3 = __builtin_amdgcn_exp2f(a[3] * LOG2E);
            lsum += (e0 + e1) + (e2 + e3);
        }
    }
    lsum += __shfl_xor(lsum, 16);
    lsum += __shfl_xor(lsum, 32);
    const float inv_l = __builtin_amdgcn_rcpf(lsum);

    f32x4 o[4];
#pragma unroll
    for (int dt = 0; dt < 4; ++dt) o[dt] = (f32x4){0.f, 0.f, 0.f, 0.f};

    // S-tile in TWO 32-key halves (acc[2] live, not acc[4] -> -8 VGPR).
    // Lane computes keys kt + h*32 + ct*16 + g*4..+3 of q-row c16; attn stored
    // directly from registers; bf16 P to LDS only for the PV transpose.
    auto computeS = [&](int t, __bf16(*Pbuf)[PSTRIDE]) {
        const int kt = t * 64;
#pragma unroll
        for (int h = 0; h < 2; ++h) {
            f32x4 acc[2];
#pragma unroll
            for (int ct = 0; ct < 2; ++ct) {
                acc[ct] = (f32x4){0.f, 0.f, 0.f, 0.f};
                const __bf16* kp =
                    kbase + (size_t)(kt + h * 32 + ct * 16 + c16) * DKD + g * 8;
                bf16x8 kf0 = *reinterpret_cast<const bf16x8*>(kp);
                bf16x8 kf1 = *reinterpret_cast<const bf16x8*>(kp + 32);
                acc[ct] = __builtin_amdgcn_mfma_f32_16x16x32_bf16(kf0, qf0, acc[ct], 0, 0, 0);
                acc[ct] = __builtin_amdgcn_mfma_f32_16x16x32_bf16(kf1, qf1, acc[ct], 0, 0, 0);
            }
#pragma unroll
            for (int ct = 0; ct < 2; ++ct) {
                f32x4 p;
                bf16x4 pb;
#pragma unroll
                for (int r = 0; r < 4; ++r) {
                    p[r] = __builtin_amdgcn_exp2f(acc[ct][r] * LOG2E) * inv_l;
                    pb[r] = (__bf16)p[r];
                }
                *reinterpret_cast<f32x4*>(
                    attn_p + (size_t)c16 * SEQ + kt + h * 32 + ct * 16 + g * 4) = p;
                *reinterpret_cast<bf16x4*>(&Pbuf[c16][h * 32 + ct * 16 + g * 4]) = pb;
            }
        }
    };

    // PV: O^T += V^T(dt-tile) x P^T; lane accumulates dims dt*16+g*4..+3 of row c16.
    auto pvTile = [&](int t, const __bf16(*Pbuf)[PSTRIDE]) {
        const int kt = t * 64;
        bf16x8 pb0 = *reinterpret_cast<const bf16x8*>(&Pbuf[c16][g * 8]);
        bf16x8 pb1 = *reinterpret_cast<const bf16x8*>(&Pbuf[c16][g * 8 + 32]);
#pragma unroll
        for (int dt = 0; dt < 4; ++dt) {
            const __bf16* vp = vbase + (size_t)(dt * 16 + c16) * SEQ + kt + g * 8;
            bf16x8 vf0 = *reinterpret_cast<const bf16x8*>(vp);
            bf16x8 vf1 = *reinterpret_cast<const bf16x8*>(vp + 32);
            o[dt] = __builtin_amdgcn_mfma_f32_16x16x32_bf16(vf0, pb0, o[dt], 0, 0, 0);
            o[dt] = __builtin_amdgcn_mfma_f32_16x16x32_bf16(vf1, pb1, o[dt], 0, 0, 0);
        }
    };

    // ---- Pass B: software-pipelined, double-buffered, wave-private (no sync) ----
    computeS(0, Pl[0][w]);
    for (int t = 1; t < 63; t += 2) {
        computeS(t, Pl[1][w]);
        pvTile(t - 1, Pl[0][w]);
        computeS(t + 1, Pl[0][w]);
        pvTile(t, Pl[1][w]);
    }
    computeS(63, Pl[1][w]);
    pvTile(62, Pl[0][w]);
    pvTile(63, Pl[1][w]);

    float* ctx_p = out_ctx + ((size_t)head * SEQ + qbase) * DKD;
#pragma unroll
    for (int dt = 0; dt < 4; ++dt)
        *reinterpret_cast<f32x4*>(ctx_p + (size_t)c16 * DKD + dt * 16 + g * 4) = o[dt];
}

extern "C" void kernel_launch(void* const* d_in, const int* in_sizes, int n_in,
                              void* d_out, int out_size, void* d_ws, size_t ws_size,
                              hipStream_t stream) {
    const float* Q = (const float*)d_in[0];
    const float* K = (const float*)d_in[1];
    const float* V = (const float*)d_in[2];
    float* out = (float*)d_out;

    const size_t nElem = (size_t)BH * SEQ * DKD;  // 4,194,304
    __bf16* Qb = (__bf16*)d_ws;
    __bf16* Kb = Qb + nElem;
    __bf16* Vt = Kb + nElem;

    float* out_ctx = out;
    float* out_attn = out + nElem;  // context first, then attn

    const int n4 = (int)(nElem / 4);
    cvt_bf16_kernel<<<dim3((n4 + 255) / 256), dim3(256), 0, stream>>>(Q, Qb, n4, 0.125f);
    cvt_bf16_kernel<<<dim3((n4 + 255) / 256), dim3(256), 0, stream>>>(K, Kb, n4, 1.0f);
    transpose_v_kernel<<<dim3(64, BH), dim3(256), 0, stream>>>(V, Vt);
    attn_kernel<<<dim3(BH * SEQ / 32), dim3(128), 0, stream>>>(Qb, Kb, Vt, out_ctx, out_attn);
}

// Round 9
// 775.923 us; speedup vs baseline: 1.0455x; 1.0358x over previous
//
#include <hip/hip_runtime.h>
#include <hip/hip_bf16.h>

// BasicAttn: B=2,H=8,S=4096,DK=64. Outputs: context (B,H,S,DK) f32 then attn (B,H,S,S) f32.
// Round 9: WAVE SPECIALIZATION. Theory: vmcnt is one in-order counter; stores
// interleaved with loads make every load-wait also wait for older store drain ->
// every structure r2-r8 pinned at ~730us. Split: compute waves (loads only in
// vmcnt) produce P into LDS; store waves (stores only, never waited) stream attn
// to HBM fillBuffer-style. Raw s_barrier handoff (NO __syncthreads = no vmcnt(0)
// drain in the loop). Pass A shared by all 4 waves (K-split halves).

typedef __bf16 bf16x8 __attribute__((ext_vector_type(8)));
typedef __bf16 bf16x4 __attribute__((ext_vector_type(4)));
typedef float f32x4 __attribute__((ext_vector_type(4)));

#define BH 16
#define SEQ 4096
#define DKD 64
#define LOG2E 1.44269504088896f

__global__ void cvt_bf16_kernel(const float* __restrict__ src,
                                __bf16* __restrict__ dst, int n4, float scale) {
    int i = blockIdx.x * blockDim.x + threadIdx.x;
    if (i < n4) {
        const float4 v = reinterpret_cast<const float4*>(src)[i];
        bf16x4 o;
        o[0] = (__bf16)(v.x * scale); o[1] = (__bf16)(v.y * scale);
        o[2] = (__bf16)(v.z * scale); o[3] = (__bf16)(v.w * scale);
        reinterpret_cast<bf16x4*>(dst)[i] = o;
    }
}

// V[head][s][d] (f32) -> Vt[head][d][s] (bf16), 64x64 tiles through LDS.
__global__ void transpose_v_kernel(const float* __restrict__ V,
                                   __bf16* __restrict__ Vt) {
    __shared__ __bf16 T[DKD][72];
    const int head = blockIdx.y;
    const int s0 = blockIdx.x * 64;
    const int t = threadIdx.x;
    const float* vp = V + ((size_t)head * SEQ + s0) * DKD;
#pragma unroll
    for (int i = 0; i < 16; ++i) {
        int j = i * 256 + t;            // j = s*64 + d, coalesced read
        T[j & 63][j >> 6] = (__bf16)vp[j];
    }
    __syncthreads();
    __bf16* op = Vt + (size_t)head * DKD * SEQ + s0;
#pragma unroll
    for (int i = 0; i < 16; ++i) {
        int j = i * 256 + t;            // j = d*64 + s, coalesced write
        op[(size_t)(j >> 6) * SEQ + (j & 63)] = T[j >> 6][j & 63];
    }
}

__global__ __launch_bounds__(256, 4) void attn_kernel(
    const __bf16* __restrict__ Qb, const __bf16* __restrict__ Kb,
    const __bf16* __restrict__ Vt, float* __restrict__ out_ctx,
    float* __restrict__ out_attn) {
    // f32 P handoff: [buf][compute-wave][row][68]; 17.4KB. Stride 68 f32 keeps
    // b128 rows 16B-aligned with 4-bank row offset.
    __shared__ __align__(16) float Pf[2][2][16][68];
    __shared__ float Lsum[4][16];

    const int tid = threadIdx.x;
    const int w = tid >> 6;      // 0,1 compute; 2,3 store
    const int lane = tid & 63;
    const int c16 = lane & 15;   // q-row within the 16-row subtile
    const int g = lane >> 4;     // key/dim 4-group (0..3)
    const int qsub = w & 1;      // q-subtile (compute w pairs with store w+2)
    const int khalf = w >> 1;    // pass-A K-half

    // XCD head affinity: xcd = wg % 8 serves heads {2*xcd, 2*xcd+1}.
    const int wg = blockIdx.x;
    const int head = ((wg & 7) << 1) | ((wg >> 3) & 1);
    const int qblk = wg >> 4;               // 0..127 (32-row blocks)
    const int qbase = qblk * 32 + qsub * 16;

    // Q fragments (B operand of swapped QK^T): Q[qbase+c16][g*8..+7], scaled 1/8.
    const __bf16* qp = Qb + ((size_t)head * SEQ + qbase + c16) * DKD + g * 8;
    const bf16x8 qf0 = *reinterpret_cast<const bf16x8*>(qp);
    const bf16x8 qf1 = *reinterpret_cast<const bf16x8*>(qp + 32);

    const __bf16* kbase = Kb + (size_t)head * SEQ * DKD;
    const __bf16* vbase = Vt + (size_t)head * DKD * SEQ;
    float* attn_p = out_attn + ((size_t)head * SEQ + qbase) * SEQ;

    // ---- Pass A (all 4 waves, K-split): per-lane sum of exp2 over 32 tiles ----
    float lsum = 0.f;
    for (int t = 0; t < 32; ++t) {
        const int kt = (khalf * 32 + t) * 64;
#pragma unroll
        for (int ct = 0; ct < 4; ++ct) {
            const __bf16* kp = kbase + (size_t)(kt + ct * 16 + c16) * DKD + g * 8;
            bf16x8 kf0 = *reinterpret_cast<const bf16x8*>(kp);
            bf16x8 kf1 = *reinterpret_cast<const bf16x8*>(kp + 32);
            f32x4 a = (f32x4){0.f, 0.f, 0.f, 0.f};
            a = __builtin_amdgcn_mfma_f32_16x16x32_bf16(kf0, qf0, a, 0, 0, 0);
            a = __builtin_amdgcn_mfma_f32_16x16x32_bf16(kf1, qf1, a, 0, 0, 0);
            float e0 = __builtin_amdgcn_exp2f(a[0] * LOG2E);
            float e1 = __builtin_amdgcn_exp2f(a[1] * LOG2E);
            float e2 = __builtin_amdgcn_exp2f(a[2] * LOG2E);
            float e3 = __builtin_amdgcn_exp2f(a[3] * LOG2E);
            lsum += (e0 + e1) + (e2 + e3);
        }
    }
    lsum += __shfl_xor(lsum, 16);
    lsum += __shfl_xor(lsum, 32);
    if (g == 0) Lsum[w][c16] = lsum;
    __syncthreads();  // pre-store-phase: vmcnt(0) drain here is loads-only, cheap

    if (w < 2) {
        // ================= COMPUTE WAVE: loads-only vmcnt stream =================
        const float inv_l = __builtin_amdgcn_rcpf(Lsum[w][c16] + Lsum[w ^ 2][c16]);

        f32x4 o[4];
#pragma unroll
        for (int dt = 0; dt < 4; ++dt) o[dt] = (f32x4){0.f, 0.f, 0.f, 0.f};

        // S-tile in two 32-key halves (acc[2] live): f32 P -> LDS buf.
        auto computeS = [&](int t, float(*Pbuf)[68]) {
            const int kt = t * 64;
#pragma unroll
            for (int h = 0; h < 2; ++h) {
                f32x4 acc[2];
#pragma unroll
                for (int ct = 0; ct < 2; ++ct) {
                    acc[ct] = (f32x4){0.f, 0.f, 0.f, 0.f};
                    const __bf16* kp =
                        kbase + (size_t)(kt + h * 32 + ct * 16 + c16) * DKD + g * 8;
                    bf16x8 kf0 = *reinterpret_cast<const bf16x8*>(kp);
                    bf16x8 kf1 = *reinterpret_cast<const bf16x8*>(kp + 32);
                    acc[ct] = __builtin_amdgcn_mfma_f32_16x16x32_bf16(kf0, qf0, acc[ct], 0, 0, 0);
                    acc[ct] = __builtin_amdgcn_mfma_f32_16x16x32_bf16(kf1, qf1, acc[ct], 0, 0, 0);
                }
#pragma unroll
                for (int ct = 0; ct < 2; ++ct) {
                    f32x4 p;
#pragma unroll
                    for (int r = 0; r < 4; ++r)
                        p[r] = __builtin_amdgcn_exp2f(acc[ct][r] * LOG2E) * inv_l;
                    *reinterpret_cast<f32x4*>(&Pbuf[c16][h * 32 + ct * 16 + g * 4]) = p;
                }
            }
        };

        // PV: read f32 P back, convert to bf16 frags, O^T += V^T x P^T.
        auto pvTile = [&](int t, const float(*Pbuf)[68]) {
            const int kt = t * 64;
            f32x4 a0 = *reinterpret_cast<const f32x4*>(&Pbuf[c16][g * 8]);
            f32x4 a1 = *reinterpret_cast<const f32x4*>(&Pbuf[c16][g * 8 + 4]);
            f32x4 b0 = *reinterpret_cast<const f32x4*>(&Pbuf[c16][g * 8 + 32]);
            f32x4 b1 = *reinterpret_cast<const f32x4*>(&Pbuf[c16][g * 8 + 36]);
            bf16x8 pb0, pb1;
#pragma unroll
            for (int j = 0; j < 4; ++j) {
                pb0[j] = (__bf16)a0[j]; pb0[j + 4] = (__bf16)a1[j];
                pb1[j] = (__bf16)b0[j]; pb1[j + 4] = (__bf16)b1[j];
            }
#pragma unroll
            for (int dt = 0; dt < 4; ++dt) {
                const __bf16* vp = vbase + (size_t)(dt * 16 + c16) * SEQ + kt + g * 8;
                bf16x8 vf0 = *reinterpret_cast<const bf16x8*>(vp);
                bf16x8 vf1 = *reinterpret_cast<const bf16x8*>(vp + 32);
                o[dt] = __builtin_amdgcn_mfma_f32_16x16x32_bf16(vf0, pb0, o[dt], 0, 0, 0);
                o[dt] = __builtin_amdgcn_mfma_f32_16x16x32_bf16(vf1, pb1, o[dt], 0, 0, 0);
            }
        };

        computeS(0, Pf[0][w]);
        asm volatile("s_waitcnt lgkmcnt(0)" ::: "memory");
        __builtin_amdgcn_s_barrier();
        for (int t = 1; t < 64; ++t) {
            computeS(t, Pf[t & 1][w]);
            pvTile(t - 1, Pf[(t - 1) & 1][w]);
            asm volatile("s_waitcnt lgkmcnt(0)" ::: "memory");
            __builtin_amdgcn_s_barrier();
        }
        pvTile(63, Pf[1][w]);

        float* ctx_p = out_ctx + ((size_t)head * SEQ + qbase) * DKD;
#pragma unroll
        for (int dt = 0; dt < 4; ++dt)
            *reinterpret_cast<f32x4*>(ctx_p + (size_t)c16 * DKD + dt * 16 + g * 4) = o[dt];
    } else {
        // ================= STORE WAVE: stores-only vmcnt stream ==================
        // Lane l: row = l>>2, 16B slot (l&3)*4; 4 instrs cover 16 rows x 256B.
        const int srow = lane >> 2;
        const int scN = (lane & 3) * 4;
        const float* srcbase = &Pf[0][w & 1][0][0];
        const float* srcalt = &Pf[1][w & 1][0][0];
        for (int t = 0; t < 64; ++t) {
            __builtin_amdgcn_s_barrier();
            __builtin_amdgcn_sched_barrier(0);
            const float* src = (t & 1) ? srcalt : srcbase;
            const int kt = t * 64;
#pragma unroll
            for (int j = 0; j < 4; ++j) {
                f32x4 v = *reinterpret_cast<const f32x4*>(src + srow * 68 + j * 16 + scN);
                *reinterpret_cast<f32x4*>(attn_p + (size_t)srow * SEQ + kt + j * 16 + scN) = v;
            }
        }
        // Stores drain at end-of-kernel; never waited on in the loop.
    }
}

extern "C" void kernel_launch(void* const* d_in, const int* in_sizes, int n_in,
                              void* d_out, int out_size, void* d_ws, size_t ws_size,
                              hipStream_t stream) {
    const float* Q = (const float*)d_in[0];
    const float* K = (const float*)d_in[1];
    const float* V = (const float*)d_in[2];
    float* out = (float*)d_out;

    const size_t nElem = (size_t)BH * SEQ * DKD;  // 4,194,304
    __bf16* Qb = (__bf16*)d_ws;
    __bf16* Kb = Qb + nElem;
    __bf16* Vt = Kb + nElem;

    float* out_ctx = out;
    float* out_attn = out + nElem;  // context first, then attn

    const int n4 = (int)(nElem / 4);
    cvt_bf16_kernel<<<dim3((n4 + 255) / 256), dim3(256), 0, stream>>>(Q, Qb, n4, 0.125f);
    cvt_bf16_kernel<<<dim3((n4 + 255) / 256), dim3(256), 0, stream>>>(K, Kb, n4, 1.0f);
    transpose_v_kernel<<<dim3(64, BH), dim3(256), 0, stream>>>(V, Vt);
    attn_kernel<<<dim3(BH * SEQ / 32), dim3(256), 0, stream>>>(Qb, Kb, Vt, out_ctx, out_attn);
}